// Round 3
// baseline (177.000 us; speedup 1.0000x reference)
//
#include <hip/hip_runtime.h>
#include <hip/hip_bf16.h>
#include <math.h>

#define BB 16
#define NN 256
#define DD 64
#define KTOP 128

typedef short s16x8 __attribute__((ext_vector_type(8)));
typedef float f32x4 __attribute__((ext_vector_type(4)));

typedef union { s16x8 v; unsigned u[4]; } frag_u;
typedef union { __hip_bfloat162 b2; unsigned u; } cvu;

__device__ __forceinline__ float asf(unsigned u){ union{unsigned u;float f;}c; c.u=u; return c.f; }

// split pair of fp32 into bf16 hi (RNE) + bf16 lo (exact residual, RNE-rounded)
__device__ __forceinline__ void split2(float v0, float v1, unsigned& hu, unsigned& lu) {
    cvu c; c.b2 = __float22bfloat162_rn(make_float2(v0, v1));
    unsigned h = c.u;
    float l0 = v0 - asf(h << 16);
    float l1 = v1 - asf(h & 0xffff0000u);
    c.b2 = __float22bfloat162_rn(make_float2(l0, l1));
    hu = h; lu = c.u;
}

// Fused: logits (split-bf16 MFMA, 3-pass) -> tanh/att_w dot -> softmax -> agg -> h -> score.
// Block = (b, 2 i's); 4 waves, wave w owns j-strip [64w, 64w+64).
// C_i[j,e] = sum_d x_j[d] * (x_i[d]*W[d,e]); A = x_j (built once), B = x_i .* W (per i).
__global__ __launch_bounds__(256, 2) void k_fused(
    const float* __restrict__ x, const float* __restrict__ W_att,
    const float* __restrict__ b_att, const float* __restrict__ att_w,
    const float* __restrict__ Wpwa, const float* __restrict__ bpwa,
    const float* __restrict__ Wpna, const float* __restrict__ bpna,
    const float* __restrict__ bnsc, const float* __restrict__ bnbi,
    const float* __restrict__ poolw, const float* __restrict__ poolb,
    float* __restrict__ hbuf, float* __restrict__ scores)
{
    const int ig = blockIdx.x;     // 0..127 : i-pair
    const int b  = blockIdx.y;     // 0..15
    const int tid = threadIdx.x;
    const int w = tid >> 6, lane = tid & 63;
    const int quad = lane >> 4, c16 = lane & 15;
    const int jb = w * 64;
    const int ibase = ig * 2;

    __shared__ float sWt[64 * 68];   // W^T: [e][d], stride 68
    __shared__ float sXi[2 * 64];    // the block's 2 x_i rows
    __shared__ float sL[2][256];     // logits rows (then softmax probs in place)
    __shared__ float sAgg[2][64];

    // ---- setup ----
    #pragma unroll
    for (int r = 0; r < 16; ++r) {
        int lin = r * 256 + tid;
        int d = lin >> 6, e = lin & 63;
        sWt[e * 68 + d] = W_att[lin];
    }
    if (tid < 128) sXi[tid] = x[(b * NN + ibase + (tid >> 6)) * DD + (tid & 63)];

    const float L2E2 = 2.8853900817779268f;  // 2*log2(e)
    float bawL[4], aww[4];
    #pragma unroll
    for (int et = 0; et < 4; ++et) {
        bawL[et] = b_att[et * 16 + c16] * L2E2;
        aww[et]  = att_w[et * 16 + c16];
    }

    // A fragments: A[m=c16][k=quad*8+t] = x[b][jb+jt*16+c16][ks*32+quad*8+t]
    frag_u Ah[4][2], Al[4][2];
    #pragma unroll
    for (int jt = 0; jt < 4; ++jt) {
        #pragma unroll
        for (int ks = 0; ks < 2; ++ks) {
            const float* xr = &x[(b * NN + jb + jt * 16 + c16) * DD + ks * 32 + quad * 8];
            float4 a0 = *(const float4*)xr;
            float4 a1 = *(const float4*)(xr + 4);
            split2(a0.x, a0.y, Ah[jt][ks].u[0], Al[jt][ks].u[0]);
            split2(a0.z, a0.w, Ah[jt][ks].u[1], Al[jt][ks].u[1]);
            split2(a1.x, a1.y, Ah[jt][ks].u[2], Al[jt][ks].u[2]);
            split2(a1.z, a1.w, Ah[jt][ks].u[3], Al[jt][ks].u[3]);
        }
    }
    __syncthreads();

    for (int ii = 0; ii < 2; ++ii) {
        float xi[2][8];
        #pragma unroll
        for (int ks = 0; ks < 2; ++ks) {
            const float* xr = &sXi[ii * 64 + ks * 32 + quad * 8];
            float4 c0 = *(const float4*)xr;
            float4 c1 = *(const float4*)(xr + 4);
            xi[ks][0]=c0.x; xi[ks][1]=c0.y; xi[ks][2]=c0.z; xi[ks][3]=c0.w;
            xi[ks][4]=c1.x; xi[ks][5]=c1.y; xi[ks][6]=c1.z; xi[ks][7]=c1.w;
        }

        f32x4 acc[4][4];
        #pragma unroll
        for (int jt = 0; jt < 4; ++jt)
            #pragma unroll
            for (int et = 0; et < 4; ++et)
                acc[jt][et] = (f32x4){0.f, 0.f, 0.f, 0.f};

        #pragma unroll
        for (int ks = 0; ks < 2; ++ks) {
            #pragma unroll
            for (int et = 0; et < 4; ++et) {
                const float* wrow = &sWt[(et * 16 + c16) * 68 + ks * 32 + quad * 8];
                float4 w0 = *(const float4*)wrow;
                float4 w1 = *(const float4*)(wrow + 4);
                frag_u bh, bl;
                split2(w0.x * xi[ks][0], w0.y * xi[ks][1], bh.u[0], bl.u[0]);
                split2(w0.z * xi[ks][2], w0.w * xi[ks][3], bh.u[1], bl.u[1]);
                split2(w1.x * xi[ks][4], w1.y * xi[ks][5], bh.u[2], bl.u[2]);
                split2(w1.z * xi[ks][6], w1.w * xi[ks][7], bh.u[3], bl.u[3]);
                #pragma unroll
                for (int jt = 0; jt < 4; ++jt) {
                    acc[jt][et] = __builtin_amdgcn_mfma_f32_16x16x32_bf16(Ah[jt][ks].v, bh.v, acc[jt][et], 0, 0, 0);
                    acc[jt][et] = __builtin_amdgcn_mfma_f32_16x16x32_bf16(Al[jt][ks].v, bh.v, acc[jt][et], 0, 0, 0);
                    acc[jt][et] = __builtin_amdgcn_mfma_f32_16x16x32_bf16(Ah[jt][ks].v, bl.v, acc[jt][et], 0, 0, 0);
                }
            }
        }

        // epilogue: p = sum_e aww*tanh(acc + baw).  tanh(u)=1-2/(exp2(L2E2*u)+1).
        float p[4][4];
        #pragma unroll
        for (int jt = 0; jt < 4; ++jt)
            #pragma unroll
            for (int r = 0; r < 4; ++r) p[jt][r] = 0.0f;

        #pragma unroll
        for (int et = 0; et < 4; ++et) {
            #pragma unroll
            for (int jt = 0; jt < 4; ++jt) {
                #pragma unroll
                for (int r = 0; r < 4; ++r) {
                    float arg = fmaf(acc[jt][et][r], L2E2, bawL[et]);
                    float m = __builtin_amdgcn_exp2f(arg);
                    float th = fmaf(-2.0f, __builtin_amdgcn_rcpf(m + 1.0f), 1.0f);
                    p[jt][r] = fmaf(aww[et], th, p[jt][r]);
                }
            }
        }

        // reduce over 16 e-lanes (xor 1,2,4,8 stays within quad); C/D row=quad*4+r
        #pragma unroll
        for (int jt = 0; jt < 4; ++jt) {
            #pragma unroll
            for (int r = 0; r < 4; ++r) {
                float s = p[jt][r];
                s += __shfl_xor(s, 1);
                s += __shfl_xor(s, 2);
                s += __shfl_xor(s, 4);
                s += __shfl_xor(s, 8);
                if (c16 == 0) sL[ii][jb + jt * 16 + quad * 4 + r] = s * 0.5f; // 1/TEMP
            }
        }
    }
    __syncthreads();

    // ---- phase 2: waves 0,1 do softmax/agg/h/score for i = ibase + w ----
    if (w < 2) {
        const int i = ibase + w;
        float* row = sL[w];
        float lg0 = row[lane], lg1 = row[lane + 64], lg2 = row[lane + 128], lg3 = row[lane + 192];
        float m = fmaxf(fmaxf(lg0, lg1), fmaxf(lg2, lg3));
        #pragma unroll
        for (int off = 32; off; off >>= 1) m = fmaxf(m, __shfl_xor(m, off));
        float e0 = __expf(lg0 - m), e1 = __expf(lg1 - m), e2 = __expf(lg2 - m), e3 = __expf(lg3 - m);
        float ssum = e0 + e1 + e2 + e3;
        #pragma unroll
        for (int off = 32; off; off >>= 1) ssum += __shfl_xor(ssum, off);
        float inv = 1.0f / ssum;
        row[lane] = e0 * inv; row[lane + 64] = e1 * inv;
        row[lane + 128] = e2 * inv; row[lane + 192] = e3 * inv;
        __asm__ volatile("s_waitcnt lgkmcnt(0)" ::: "memory");

        float agg = 0.0f;
        const float4* A4 = (const float4*)row;
        const float* xb = &x[(b * NN) * DD];
        #pragma unroll 8
        for (int jq = 0; jq < 64; ++jq) {
            float4 a = A4[jq];
            int j = jq * 4;
            agg = fmaf(a.x, xb[(j + 0) * DD + lane], agg);
            agg = fmaf(a.y, xb[(j + 1) * DD + lane], agg);
            agg = fmaf(a.z, xb[(j + 2) * DD + lane], agg);
            agg = fmaf(a.w, xb[(j + 3) * DD + lane], agg);
        }
        sAgg[w][lane] = agg;
        __asm__ volatile("s_waitcnt lgkmcnt(0)" ::: "memory");

        double hacc = (double)bpwa[lane] + (double)bpna[lane];
        #pragma unroll 4
        for (int d = 0; d < 64; ++d) {
            hacc += (double)sAgg[w][d] * (double)Wpwa[d * DD + lane]
                  + (double)sXi[w * 64 + d] * (double)Wpna[d * DD + lane];
        }
        const double bnmul = 0.99999500003749968750e0; // 1/sqrt(1+1e-5)
        double hb = hacc * ((double)bnsc[lane] * bnmul) + (double)bnbi[lane];
        float hf = (float)hb;
        const float LAM = 1.0507009873554805f, ALP = 1.6732632423543772f;
        float hs = hf > 0.0f ? LAM * hf : LAM * ALP * (__expf(hf) - 1.0f);
        hbuf[((b * NN) + i) * DD + lane] = hs;

        double z = (double)hs * (double)poolw[lane];
        #pragma unroll
        for (int off = 32; off; off >>= 1) z += __shfl_xor(z, off);
        if (lane == 0) {
            double zz = z + (double)poolb[0];
            scores[b * NN + i] = (float)(1.0 / (1.0 + exp(-zz)));
        }
    }
}

// per-batch bitonic sort of 256 scores (desc, tie: lower idx first) + gather top-128.
__global__ __launch_bounds__(256) void k_topk(
    const float* __restrict__ scores, const float* __restrict__ hbuf,
    float* __restrict__ out)
{
    const int b = blockIdx.x;
    const int t = threadIdx.x;
    __shared__ float ss[256];
    __shared__ int   si[256];
    ss[t] = scores[b * NN + t];
    si[t] = t;
    __syncthreads();
    for (int k = 2; k <= 256; k <<= 1) {
        for (int j = k >> 1; j > 0; j >>= 1) {
            int p = t ^ j;
            if (p > t) {
                float a = ss[t], c = ss[p];
                int ia = si[t], ic = si[p];
                bool desc = ((t & k) == 0);
                bool aFirst = (a > c) || (a == c && ia < ic);
                bool dosw = desc ? (!aFirst) : aFirst;
                if (dosw) { ss[t] = c; ss[p] = a; si[t] = ic; si[p] = ia; }
            }
            __syncthreads();
        }
    }
    for (int m = t; m < KTOP * DD; m += 256) {
        int r = m >> 6, e = m & 63;
        out[(b * KTOP + r) * DD + e] = hbuf[((b * NN) + si[r]) * DD + e] * ss[r];
    }
}

extern "C" void kernel_launch(void* const* d_in, const int* in_sizes, int n_in,
                              void* d_out, int out_size, void* d_ws, size_t ws_size,
                              hipStream_t stream) {
    const float* x        = (const float*)d_in[0];
    const float* W_att    = (const float*)d_in[1];
    const float* b_att    = (const float*)d_in[2];
    const float* att_w    = (const float*)d_in[3];
    const float* W_pwa    = (const float*)d_in[4];
    const float* b_pwa    = (const float*)d_in[5];
    const float* W_pna    = (const float*)d_in[6];
    const float* b_pna    = (const float*)d_in[7];
    const float* bn_scale = (const float*)d_in[8];
    const float* bn_bias  = (const float*)d_in[9];
    const float* pool_w   = (const float*)d_in[10];
    const float* pool_b   = (const float*)d_in[11];

    float* hbuf    = (float*)d_ws;                 // 16*256*64
    float* scoresW = hbuf + BB * NN * DD;          // 16*256
    float* out     = (float*)d_out;

    k_fused<<<dim3(128, BB), 256, 0, stream>>>(x, W_att, b_att, att_w,
                                               W_pwa, b_pwa, W_pna, b_pna,
                                               bn_scale, bn_bias, pool_w, pool_b,
                                               hbuf, scoresW);
    k_topk<<<dim3(BB), 256, 0, stream>>>(scoresW, hbuf, out);
}

// Round 4
// 154.782 us; speedup vs baseline: 1.1435x; 1.1435x over previous
//
#include <hip/hip_runtime.h>
#include <hip/hip_bf16.h>
#include <math.h>

#define BB 16
#define NN 256
#define DD 64
#define KTOP 128

typedef short s16x8 __attribute__((ext_vector_type(8)));
typedef float f32x4 __attribute__((ext_vector_type(4)));

typedef union { s16x8 v; unsigned u[4]; } frag_u;
typedef union { __hip_bfloat162 b2; unsigned u; } cvu;

__device__ __forceinline__ float asf(unsigned u){ union{unsigned u;float f;}c; c.u=u; return c.f; }

// split pair of fp32 into bf16 hi (RNE) + bf16 lo (residual, RNE)
__device__ __forceinline__ void split2(float v0, float v1, unsigned& hu, unsigned& lu) {
    cvu c; c.b2 = __float22bfloat162_rn(make_float2(v0, v1));
    unsigned h = c.u;
    float l0 = v0 - asf(h << 16);
    float l1 = v1 - asf(h & 0xffff0000u);
    c.b2 = __float22bfloat162_rn(make_float2(l0, l1));
    hu = h; lu = c.u;
}

// Fused: logits (split-bf16 MFMA, 3-pass) -> tanh/att_w dot -> softmax -> agg -> h -> score.
// Block = (b, 4 i's) [round-2 amortization]; 4 waves, wave w owns j-strip [64w, 64w+64) in
// phase 1 and row i=ibase+w in phase 2.
__global__ __launch_bounds__(256, 2) void k_fused(
    const float* __restrict__ x, const float* __restrict__ W_att,
    const float* __restrict__ b_att, const float* __restrict__ att_w,
    const float* __restrict__ Wpwa, const float* __restrict__ bpwa,
    const float* __restrict__ Wpna, const float* __restrict__ bpna,
    const float* __restrict__ bnsc, const float* __restrict__ bnbi,
    const float* __restrict__ poolw, const float* __restrict__ poolb,
    float* __restrict__ hbuf, float* __restrict__ scores)
{
    const int ig = blockIdx.x;     // 0..63 : i-group of 4
    const int b  = blockIdx.y;     // 0..15
    const int tid = threadIdx.x;
    const int w = tid >> 6, lane = tid & 63;
    const int quad = lane >> 4, c16 = lane & 15;
    const int jb = w * 64;
    const int ibase = ig * 4;

    __shared__ float sWt[64 * 68];   // W^T: [e][d], stride 68
    __shared__ float sXi[4 * 64];    // the block's 4 x_i rows
    __shared__ float sL[4][256];     // logit rows
    __shared__ float sAgg[4][64];

    // ---- setup (once per block) ----
    #pragma unroll
    for (int r = 0; r < 16; ++r) {
        int lin = r * 256 + tid;
        int d = lin >> 6, e = lin & 63;
        sWt[e * 68 + d] = W_att[lin];
    }
    sXi[tid] = x[(b * NN + ibase + (tid >> 6)) * DD + (tid & 63)];

    const float L2E2 = 2.8853900817779268f;  // 2*log2(e)
    float bawL[4], aww[4];
    #pragma unroll
    for (int et = 0; et < 4; ++et) {
        bawL[et] = b_att[et * 16 + c16] * L2E2;
        aww[et]  = att_w[et * 16 + c16];
    }

    // A fragments: A[m=c16][k=quad*8+t] = x[b][jb+jt*16+c16][ks*32+quad*8+t]
    frag_u Ah[4][2], Al[4][2];
    #pragma unroll
    for (int jt = 0; jt < 4; ++jt) {
        #pragma unroll
        for (int ks = 0; ks < 2; ++ks) {
            const float* xr = &x[(b * NN + jb + jt * 16 + c16) * DD + ks * 32 + quad * 8];
            float4 a0 = *(const float4*)xr;
            float4 a1 = *(const float4*)(xr + 4);
            split2(a0.x, a0.y, Ah[jt][ks].u[0], Al[jt][ks].u[0]);
            split2(a0.z, a0.w, Ah[jt][ks].u[1], Al[jt][ks].u[1]);
            split2(a1.x, a1.y, Ah[jt][ks].u[2], Al[jt][ks].u[2]);
            split2(a1.z, a1.w, Ah[jt][ks].u[3], Al[jt][ks].u[3]);
        }
    }
    __syncthreads();

    for (int ii = 0; ii < 4; ++ii) {
        float xi[2][8];
        #pragma unroll
        for (int ks = 0; ks < 2; ++ks) {
            const float* xr = &sXi[ii * 64 + ks * 32 + quad * 8];
            float4 c0 = *(const float4*)xr;
            float4 c1 = *(const float4*)(xr + 4);
            xi[ks][0]=c0.x; xi[ks][1]=c0.y; xi[ks][2]=c0.z; xi[ks][3]=c0.w;
            xi[ks][4]=c1.x; xi[ks][5]=c1.y; xi[ks][6]=c1.z; xi[ks][7]=c1.w;
        }

        f32x4 acc[4][4];
        #pragma unroll
        for (int jt = 0; jt < 4; ++jt)
            #pragma unroll
            for (int et = 0; et < 4; ++et)
                acc[jt][et] = (f32x4){0.f, 0.f, 0.f, 0.f};

        #pragma unroll
        for (int ks = 0; ks < 2; ++ks) {
            #pragma unroll
            for (int et = 0; et < 4; ++et) {
                const float* wrow = &sWt[(et * 16 + c16) * 68 + ks * 32 + quad * 8];
                float4 w0 = *(const float4*)wrow;
                float4 w1 = *(const float4*)(wrow + 4);
                frag_u bh, bl;
                split2(w0.x * xi[ks][0], w0.y * xi[ks][1], bh.u[0], bl.u[0]);
                split2(w0.z * xi[ks][2], w0.w * xi[ks][3], bh.u[1], bl.u[1]);
                split2(w1.x * xi[ks][4], w1.y * xi[ks][5], bh.u[2], bl.u[2]);
                split2(w1.z * xi[ks][6], w1.w * xi[ks][7], bh.u[3], bl.u[3]);
                #pragma unroll
                for (int jt = 0; jt < 4; ++jt) {
                    acc[jt][et] = __builtin_amdgcn_mfma_f32_16x16x32_bf16(Ah[jt][ks].v, bh.v, acc[jt][et], 0, 0, 0);
                    acc[jt][et] = __builtin_amdgcn_mfma_f32_16x16x32_bf16(Al[jt][ks].v, bh.v, acc[jt][et], 0, 0, 0);
                    acc[jt][et] = __builtin_amdgcn_mfma_f32_16x16x32_bf16(Ah[jt][ks].v, bl.v, acc[jt][et], 0, 0, 0);
                }
            }
        }

        // epilogue: p = sum_e aww*tanh(acc + baw);  tanh(u)=1-2/(exp2(L2E2*u)+1)
        float p[4][4];
        #pragma unroll
        for (int jt = 0; jt < 4; ++jt)
            #pragma unroll
            for (int r = 0; r < 4; ++r) p[jt][r] = 0.0f;

        #pragma unroll
        for (int et = 0; et < 4; ++et) {
            #pragma unroll
            for (int jt = 0; jt < 4; ++jt) {
                #pragma unroll
                for (int r = 0; r < 4; ++r) {
                    float arg = fmaf(acc[jt][et][r], L2E2, bawL[et]);
                    float m = __builtin_amdgcn_exp2f(arg);
                    float th = fmaf(-2.0f, __builtin_amdgcn_rcpf(m + 1.0f), 1.0f);
                    p[jt][r] = fmaf(aww[et], th, p[jt][r]);
                }
            }
        }

        // reduce over 16 e-lanes (xor 1,2,4,8 stays within quad); C/D row=quad*4+r
        #pragma unroll
        for (int jt = 0; jt < 4; ++jt) {
            #pragma unroll
            for (int r = 0; r < 4; ++r) {
                float s = p[jt][r];
                s += __shfl_xor(s, 1);
                s += __shfl_xor(s, 2);
                s += __shfl_xor(s, 4);
                s += __shfl_xor(s, 8);
                if (c16 == 0) sL[ii][jb + jt * 16 + quad * 4 + r] = s * 0.5f; // 1/TEMP
            }
        }
    }
    __syncthreads();

    // ---- phase 2: wave w does softmax/agg/h/score for i = ibase + w ----
    {
        const int i = ibase + w;
        float* row = sL[w];
        float lg0 = row[lane], lg1 = row[lane + 64], lg2 = row[lane + 128], lg3 = row[lane + 192];
        float m = fmaxf(fmaxf(lg0, lg1), fmaxf(lg2, lg3));
        #pragma unroll
        for (int off = 32; off; off >>= 1) m = fmaxf(m, __shfl_xor(m, off));
        float e0 = __expf(lg0 - m), e1 = __expf(lg1 - m), e2 = __expf(lg2 - m), e3 = __expf(lg3 - m);
        float ssum = e0 + e1 + e2 + e3;
        #pragma unroll
        for (int off = 32; off; off >>= 1) ssum += __shfl_xor(ssum, off);
        float inv = 1.0f / ssum;
        row[lane] = e0 * inv; row[lane + 64] = e1 * inv;
        row[lane + 128] = e2 * inv; row[lane + 192] = e3 * inv;
        __asm__ volatile("s_waitcnt lgkmcnt(0)" ::: "memory");

        float agg = 0.0f;
        const float4* A4 = (const float4*)row;
        const float* xb = &x[(b * NN) * DD];
        #pragma unroll 8
        for (int jq = 0; jq < 64; ++jq) {
            float4 a = A4[jq];
            int j = jq * 4;
            agg = fmaf(a.x, xb[(j + 0) * DD + lane], agg);
            agg = fmaf(a.y, xb[(j + 1) * DD + lane], agg);
            agg = fmaf(a.z, xb[(j + 2) * DD + lane], agg);
            agg = fmaf(a.w, xb[(j + 3) * DD + lane], agg);
        }
        sAgg[w][lane] = agg;
        __asm__ volatile("s_waitcnt lgkmcnt(0)" ::: "memory");

        double hacc = (double)bpwa[lane] + (double)bpna[lane];
        #pragma unroll 4
        for (int d = 0; d < 64; ++d) {
            hacc += (double)sAgg[w][d] * (double)Wpwa[d * DD + lane]
                  + (double)sXi[w * 64 + d] * (double)Wpna[d * DD + lane];
        }
        const double bnmul = 0.99999500003749968750e0; // 1/sqrt(1+1e-5)
        double hb = hacc * ((double)bnsc[lane] * bnmul) + (double)bnbi[lane];
        float hf = (float)hb;
        const float LAM = 1.0507009873554805f, ALP = 1.6732632423543772f;
        float hs = hf > 0.0f ? LAM * hf : LAM * ALP * (__expf(hf) - 1.0f);
        hbuf[((b * NN) + i) * DD + lane] = hs;

        double z = (double)hs * (double)poolw[lane];
        #pragma unroll
        for (int off = 32; off; off >>= 1) z += __shfl_xor(z, off);
        if (lane == 0) {
            double zz = z + (double)poolb[0];
            scores[b * NN + i] = (float)(1.0 / (1.0 + exp(-zz)));
        }
    }
}

// per-batch rank-selection topk (score desc, tie: lower idx first) + coalesced gather.
__global__ __launch_bounds__(256) void k_topk(
    const float* __restrict__ scores, const float* __restrict__ hbuf,
    float* __restrict__ out)
{
    const int b = blockIdx.x;
    const int t = threadIdx.x;
    __shared__ float ss[256];
    __shared__ int   perm[KTOP];
    ss[t] = scores[b * NN + t];
    __syncthreads();
    const float my = ss[t];
    int rank = 0;
    #pragma unroll 8
    for (int j = 0; j < 256; ++j) {
        float v = ss[j];
        rank += (v > my) || (v == my && j < t);
    }
    if (rank < KTOP) perm[rank] = t;
    __syncthreads();
    #pragma unroll
    for (int m = t; m < KTOP * DD; m += 256) {
        int r = m >> 6, e = m & 63;
        int i = perm[r];
        out[(b * KTOP + r) * DD + e] = hbuf[((b * NN) + i) * DD + e] * ss[i];
    }
}

extern "C" void kernel_launch(void* const* d_in, const int* in_sizes, int n_in,
                              void* d_out, int out_size, void* d_ws, size_t ws_size,
                              hipStream_t stream) {
    const float* x        = (const float*)d_in[0];
    const float* W_att    = (const float*)d_in[1];
    const float* b_att    = (const float*)d_in[2];
    const float* att_w    = (const float*)d_in[3];
    const float* W_pwa    = (const float*)d_in[4];
    const float* b_pwa    = (const float*)d_in[5];
    const float* W_pna    = (const float*)d_in[6];
    const float* b_pna    = (const float*)d_in[7];
    const float* bn_scale = (const float*)d_in[8];
    const float* bn_bias  = (const float*)d_in[9];
    const float* pool_w   = (const float*)d_in[10];
    const float* pool_b   = (const float*)d_in[11];

    float* hbuf    = (float*)d_ws;                 // 16*256*64
    float* scoresW = hbuf + BB * NN * DD;          // 16*256
    float* out     = (float*)d_out;

    k_fused<<<dim3(64, BB), 256, 0, stream>>>(x, W_att, b_att, att_w,
                                              W_pwa, b_pwa, W_pna, b_pna,
                                              bn_scale, bn_bias, pool_w, pool_b,
                                              hbuf, scoresW);
    k_topk<<<dim3(BB), 256, 0, stream>>>(scoresW, hbuf, out);
}